// Round 7
// baseline (168.668 us; speedup 1.0000x reference)
//
#include <hip/hip_runtime.h>

// Problem constants
#define NBANDS 8
#define BS 32
#define MTF 41
#define IMG 552
#define CONV 512
#define QOUT 481
#define NIMG 32
#define NN 1024.0f

// Transposed fp16 input T: [NIMG][TX][TY], zero-padded
#define TX 560
#define TY 576

typedef _Float16 half8 __attribute__((ext_vector_type(8)));
typedef float f32x16 __attribute__((ext_vector_type(16)));

// ---------- prep 1: transpose + fp16 convert ----------
__global__ __launch_bounds__(256) void prep_transpose(
    const float* __restrict__ in, _Float16* __restrict__ T)
{
    __shared__ _Float16 s[64][72];
    int bid = blockIdx.x;
    int img = bid / 81;            // 9x9 tiles of 64
    int t = bid % 81;
    int ty = t / 9, tx2 = t % 9;
    int y0 = ty * 64, x0 = tx2 * 64;
    const float* ip = in + (size_t)img * IMG * IMG;

    for (int k = 0; k < 16; ++k) {
        int i = k * 256 + threadIdx.x;
        int r = i >> 6, c = i & 63;
        int y = y0 + r, x = x0 + c;
        float v = (y < IMG && x < IMG) ? ip[(size_t)y * IMG + x] : 0.f;
        s[c][r] = (_Float16)v;
    }
    __syncthreads();
    _Float16* Tp = T + (size_t)img * TX * TY;
    for (int k = 0; k < 2; ++k) {
        int i = k * 256 + threadIdx.x;  // 512 = 64 xi * 8 g
        int xi = i >> 3, g = i & 7;
        int x = x0 + xi;
        if (x < TX) {
            half8 v = *(const half8*)&s[xi][g * 8];
            *(half8*)&Tp[(size_t)x * TY + y0 + g * 8] = v;
        }
    }
}

// ---------- prep 2: Toeplitz A-table for 32x32x16 MFMA ----------
// A[i][kabs] = w[kabs - i][kx], i = out-row (0..31), kabs = 0..79 (5 slabs of 16)
// frag layout: lane l: row i = l&31, k = 16*s + (l>>5)*8 + j
__global__ __launch_bounds__(320) void prep_atab32(
    const float* __restrict__ w, _Float16* __restrict__ A)
{
    int bid = blockIdx.x;                 // band*41 + kx
    int band = bid / MTF, kx = bid % MTF;
    int s = threadIdx.x >> 6, lane = threadIdx.x & 63;
    int i = lane & 31;
    int kb = 16 * s + ((lane >> 5) << 3);
    const float* wp = w + band * MTF * MTF;
    half8 v;
#pragma unroll
    for (int j = 0; j < 8; ++j) {
        int ky = kb + j - i;
        v[j] = (ky >= 0 && ky < MTF) ? (_Float16)wp[ky * MTF + kx] : (_Float16)0.f;
    }
    *(half8*)&A[(((size_t)bid * 5 + s) << 9) + lane * 8] = v;
}

// ---------- Kernel A: 32x32x16 MFMA conv, 3-deep A prefetch ----------
// Block: 4 waves, 64y x 128x outputs (wave = 64y x 32x).
// LDS: 14 y-slabs x 168 x-cols, half8-packed: 37632 B.
#define XP2 168

__global__ __launch_bounds__(256, 3) void conv_mfma64x(
    const _Float16* __restrict__ T, const _Float16* __restrict__ Atab,
    float* __restrict__ out)
{
    extern __shared__ _Float16 sB[];   // 14*168*8 halfs = 37632 B
    int bid = blockIdx.x;
    int img = bid >> 5;
    int rr  = bid & 31;
    int yb  = rr >> 2, xb = rr & 3;
    int y0 = yb << 6;          // 0..448
    int x0 = xb << 7;          // 0..384
    int band = img & 7;
    int tid = threadIdx.x;

    const _Float16* Tp = T + (size_t)img * TX * TY;
    for (int e = tid; e < 14 * XP2; e += 256) {
        int g = e / XP2, x = e - g * XP2;
        half8 v = *(const half8*)&Tp[(size_t)(x0 + x) * TY + y0 + g * 8];
        *(half8*)&sB[(size_t)e * 8] = v;
    }
    __syncthreads();

    int l  = tid & 63;
    int wx = tid >> 6;          // 0..3 (x sub-tile)
    int l5 = l >> 5;
    int ln = l & 31;

    const half8* Ab = (const half8*)(Atab + (((size_t)band * MTF * 5) << 9)) + l;
    int base = l5 * XP2 + ln + (wx << 5);   // 16B units

    f32x16 a0 = {}, a1 = {};

    auto LDA = [&](half8 (&A)[5], int kx) {
        const half8* q = Ab + (size_t)kx * 5 * 64;
#pragma unroll
        for (int s = 0; s < 5; ++s) A[s] = q[(size_t)s * 64];
    };

    auto body = [&](half8 (&A)[5], int kx) {
        const char* p = (const char*)sB + ((size_t)(base + kx) << 4);
        half8 B[7];
#pragma unroll
        for (int b = 0; b < 7; ++b) B[b] = *(const half8*)(p + b * (2 * XP2 * 16));
#pragma unroll
        for (int s = 0; s < 5; ++s) {
            a0 = __builtin_amdgcn_mfma_f32_32x32x16_f16(A[s], B[s],     a0, 0, 0, 0);
            a1 = __builtin_amdgcn_mfma_f32_32x32x16_f16(A[s], B[s + 2], a1, 0, 0, 0);
        }
    };

    half8 A0[5], A1[5], A2[5];
    LDA(A0, 0);
    LDA(A1, 1);
#pragma unroll 1
    for (int kx = 0; kx < 39; kx += 3) {
        LDA(A2, kx + 2);
        body(A0, kx);
        LDA(A0, kx + 3);
        body(A1, kx + 1);
        LDA(A1, kx + 4);          // max arg = 36+4 = 40
        body(A2, kx + 2);
    }
    body(A0, 39);
    body(A1, 40);

    // C/D layout (32x32): col = l&31, row = (r&3) + 8*(r>>2) + 4*(l>>5)
    float* op = out + (size_t)img * CONV * CONV;
    int colb = x0 + (wx << 5) + ln;
    int rb   = y0 + (l5 << 2);
#pragma unroll
    for (int r2 = 0; r2 < 16; ++r2) {
        int rowo = (r2 & 3) + ((r2 >> 2) << 3);
        op[(size_t)(rb + rowo) * CONV + colb]      = a0[r2];
        op[(size_t)(rb + 32 + rowo) * CONV + colb] = a1[r2];
    }
}

// ---------------- Kernel B: wave-streaming box-sums + Q ----------------
// 256-thr blocks, 2048 blocks -> 8192 waves = 32 waves/CU full residency.
// Wave: 64 input cols -> 32 output cols, 1 chain, 31-row strip.
template<int C, int RM, int BM, bool BC>
__device__ __forceinline__ float dppadd(float v) {
    int t = __builtin_amdgcn_update_dpp(0, __builtin_bit_cast(int, v), C, RM, BM, BC);
    return v + __builtin_bit_cast(float, t);
}

__device__ __forceinline__ float wave_iscan(float v) {
    v = dppadd<0x111, 0xf, 0xf, true >(v);   // row_shr:1
    v = dppadd<0x112, 0xf, 0xf, true >(v);   // row_shr:2
    v = dppadd<0x114, 0xf, 0xf, true >(v);   // row_shr:4
    v = dppadd<0x118, 0xf, 0xf, true >(v);   // row_shr:8
    v = dppadd<0x142, 0xa, 0xf, false>(v);   // row_bcast:15 -> rows 1,3
    v = dppadd<0x143, 0xc, 0xf, false>(v);   // row_bcast:31 -> rows 2,3
    return v;
}

__device__ __forceinline__ float win32(float s, int lane) {
    float P = wave_iscan(s);
    float Pg = __shfl(P, lane + 31, 64);
    return Pg - P + s;
}

__device__ __forceinline__ float qval(float A0, float A1, float A2, float A3) {
    float mul = A0 * A1;
    float sq  = fmaf(A0, A0, A1 * A1);
    float num = 4.f * fmaf(NN, A3, -mul) * mul;
    float dt  = fmaf(NN, A2, -sq);
    float den = dt * sq;
    bool  c1  = (dt == 0.f) && (sq != 0.f);
    float nn = num, dd = den;
    if (den == 0.f) { nn = c1 ? 2.f * mul : 1.f; dd = c1 ? sq : 1.f; }
    return nn * __builtin_amdgcn_rcpf(dd);
}

#define SROWS 31

__global__ __launch_bounds__(256) void box_q_wave1(
    const float* __restrict__ o,     // [NIMG][512][512]
    const float* __restrict__ lab,   // [NIMG][512][512]
    double* __restrict__ acc)        // acc[NIMG]
{
    int bid   = blockIdx.x;
    int img   = bid >> 6;
    int strip = (bid >> 2) & 15;
    int xblk  = bid & 3;
    int wid   = threadIdx.x >> 6;
    int lane  = threadIdx.x & 63;

    int c0 = xblk * 128 + wid * 32;
    int c  = c0 + lane;
    bool cvalid = c < CONV;
    int r0 = strip * SROWS;
    int nrows = min(SROWS, QOUT - r0);

    const float* op = o   + (size_t)img * CONV * CONV + c;
    const float* lp = lab + (size_t)img * CONV * CONV + c;

    float s0 = 0.f, s1 = 0.f, s2 = 0.f, s3 = 0.f;
#pragma unroll 4
    for (int r = r0; r < r0 + BS; ++r) {
        float ov = cvalid ? op[(size_t)r * CONV] : 0.f;
        float lv = cvalid ? lp[(size_t)r * CONV] : 0.f;
        s0 += ov; s1 += lv;
        s2 = fmaf(ov, ov, fmaf(lv, lv, s2));
        s3 = fmaf(ov, lv, s3);
    }

    int x = c0 + lane;
    bool xvalid = (lane < 32) && (x < QOUT);
    float qacc = 0.f;

#pragma unroll 1
    for (int i = 0;; ++i) {
        float oa = 0.f, la = 0.f, ob = 0.f, lb = 0.f;
        bool more = (i + 1 < nrows);
        if (more && cvalid) {
            int radd = r0 + i + BS, rsub = r0 + i;
            oa = op[(size_t)radd * CONV]; la = lp[(size_t)radd * CONV];
            ob = op[(size_t)rsub * CONV]; lb = lp[(size_t)rsub * CONV];
        }

        float A0 = win32(s0, lane);
        float A1 = win32(s1, lane);
        float A2 = win32(s2, lane);
        float A3 = win32(s3, lane);

        if (xvalid) qacc += qval(A0, A1, A2, A3);

        if (!more) break;
        s0 += oa - ob;
        s1 += la - lb;
        s2 = fmaf(oa, oa, fmaf(la, la, fmaf(ob, -ob, fmaf(lb, -lb, s2))));
        s3 = fmaf(oa, la, fmaf(ob, -lb, s3));
    }

    qacc += __shfl_down(qacc, 16, 64);
    qacc += __shfl_down(qacc, 8, 64);
    qacc += __shfl_down(qacc, 4, 64);
    qacc += __shfl_down(qacc, 2, 64);
    qacc += __shfl_down(qacc, 1, 64);
    if (lane == 0) atomicAdd(&acc[img], (double)qacc);
}

__global__ void finalize_kernel(const double* __restrict__ acc, float* __restrict__ out)
{
    double t = 0.0;
    for (int i = 0; i < NIMG; ++i) t += acc[i];
    out[0] = 1.0f - (float)(t / 7403552.0);   // 4*8*481*481
}

extern "C" void kernel_launch(void* const* d_in, const int* in_sizes, int n_in,
                              void* d_out, int out_size, void* d_ws, size_t ws_size,
                              hipStream_t stream)
{
    const float* outputs = (const float*)d_in[0];   // [4,8,552,552]
    const float* labels  = (const float*)d_in[1];   // [4,8,512,512]
    const float* mtf     = (const float*)d_in[2];   // [8,1,41,41]

    double*    acc   = (double*)d_ws;                                   // @0
    float*     o_buf = (float*)((char*)d_ws + 4096);                    // 33.55 MB
    _Float16*  T     = (_Float16*)((char*)d_ws + 4096 + 33554432);      // 20.64 MB
    _Float16*  Atab  = (_Float16*)((char*)d_ws + 4096 + 33554432 + 20643840); // 1.68 MB

    hipMemsetAsync(d_ws, 0, 256, stream);

    prep_transpose<<<NIMG * 81, 256, 0, stream>>>(outputs, T);
    prep_atab32<<<NBANDS * MTF, 320, 0, stream>>>(mtf, Atab);
    conv_mfma64x<<<NIMG * 32, 256, 14 * XP2 * 16, stream>>>(T, Atab, o_buf);
    box_q_wave1<<<NIMG * 64, 256, 0, stream>>>(o_buf, labels, acc);
    finalize_kernel<<<1, 1, 0, stream>>>(acc, (float*)d_out);
}

// Round 8
// 139.296 us; speedup vs baseline: 1.2109x; 1.2109x over previous
//
#include <hip/hip_runtime.h>

// Problem constants
#define NBANDS 8
#define BS 32
#define MTF 41
#define IMG 552
#define CONV 512
#define QOUT 481
#define NIMG 32
#define NN 1024.0f
#define KXP 42            // Atab kx entries per band (41 real + 1 zero pad)

// Transposed fp16 input T: [NIMG][TX][TY], zero-padded
#define TX 560
#define TY 576

typedef _Float16 half8 __attribute__((ext_vector_type(8)));
typedef float f32x16 __attribute__((ext_vector_type(16)));

// ---------- prep 1: transpose + fp16 convert ----------
__global__ __launch_bounds__(256) void prep_transpose(
    const float* __restrict__ in, _Float16* __restrict__ T)
{
    __shared__ _Float16 s[64][72];
    int bid = blockIdx.x;
    int img = bid / 81;            // 9x9 tiles of 64
    int t = bid % 81;
    int ty = t / 9, tx2 = t % 9;
    int y0 = ty * 64, x0 = tx2 * 64;
    const float* ip = in + (size_t)img * IMG * IMG;

    for (int k = 0; k < 16; ++k) {
        int i = k * 256 + threadIdx.x;
        int r = i >> 6, c = i & 63;
        int y = y0 + r, x = x0 + c;
        float v = (y < IMG && x < IMG) ? ip[(size_t)y * IMG + x] : 0.f;
        s[c][r] = (_Float16)v;
    }
    __syncthreads();
    _Float16* Tp = T + (size_t)img * TX * TY;
    for (int k = 0; k < 2; ++k) {
        int i = k * 256 + threadIdx.x;  // 512 = 64 xi * 8 g
        int xi = i >> 3, g = i & 7;
        int x = x0 + xi;
        if (x < TX) {
            half8 v = *(const half8*)&s[xi][g * 8];
            *(half8*)&Tp[(size_t)x * TY + y0 + g * 8] = v;
        }
    }
}

// ---------- prep 2: Toeplitz A-table for 32x32x16 MFMA (42 kx, last = zeros) ----------
// A[i][kabs] = w[kabs - i][kx], i = out-row (0..31), kabs = 0..79 (5 slabs of 16)
// frag layout: lane l: row i = l&31, k = 16*s + (l>>5)*8 + j
__global__ __launch_bounds__(320) void prep_atab32(
    const float* __restrict__ w, _Float16* __restrict__ A)
{
    int bid = blockIdx.x;                 // band*KXP + kx
    int band = bid / KXP, kx = bid % KXP;
    int s = threadIdx.x >> 6, lane = threadIdx.x & 63;
    int i = lane & 31;
    int kb = 16 * s + ((lane >> 5) << 3);
    const float* wp = w + band * MTF * MTF;
    half8 v;
#pragma unroll
    for (int j = 0; j < 8; ++j) {
        int ky = kb + j - i;
        v[j] = (kx < MTF && ky >= 0 && ky < MTF) ? (_Float16)wp[ky * MTF + kx]
                                                 : (_Float16)0.f;
    }
    *(half8*)&A[(((size_t)bid * 5 + s) << 9) + lane * 8] = v;
}

// ---------- Kernel A: 32x32x16 MFMA conv, 4 accumulator chains ----------
// Block: 4 waves, 64y x 128x outputs (wave = 64y x 32x).
// LDS: 14 y-slabs x 168 x-cols, half8-packed: 37632 B.
#define XP2 168

__global__ __launch_bounds__(256, 3) void conv_mfma4c(
    const _Float16* __restrict__ T, const _Float16* __restrict__ Atab,
    float* __restrict__ out)
{
    extern __shared__ _Float16 sB[];   // 14*168*8 halfs = 37632 B
    int bid = blockIdx.x;
    int img = bid >> 5;
    int rr  = bid & 31;
    int yb  = rr >> 2, xb = rr & 3;
    int y0 = yb << 6;          // 0..448
    int x0 = xb << 7;          // 0..384
    int band = img & 7;
    int tid = threadIdx.x;

    const _Float16* Tp = T + (size_t)img * TX * TY;
    for (int e = tid; e < 14 * XP2; e += 256) {
        int g = e / XP2, x = e - g * XP2;
        half8 v = *(const half8*)&Tp[(size_t)(x0 + x) * TY + y0 + g * 8];
        *(half8*)&sB[(size_t)e * 8] = v;
    }
    __syncthreads();

    int l  = tid & 63;
    int wx = tid >> 6;          // 0..3 (x sub-tile)
    int l5 = l >> 5;
    int ln = l & 31;

    const half8* Ab = (const half8*)(Atab + (((size_t)band * KXP * 5) << 9)) + l;
    int base = l5 * XP2 + ln + (wx << 5);   // 16B units

    // 4 independent MFMA chains: (a0,a1) x (even,odd slab parity)
    f32x16 a0e = {}, a0o = {}, a1e = {}, a1o = {};

    auto LDA = [&](half8 (&A)[5], int kx) {
        const half8* q = Ab + (size_t)kx * 5 * 64;
#pragma unroll
        for (int s = 0; s < 5; ++s) A[s] = q[(size_t)s * 64];
    };

    auto body = [&](half8 (&A)[5], int kx) {
        const char* p = (const char*)sB + ((size_t)(base + kx) << 4);
        half8 B[7];
#pragma unroll
        for (int b = 0; b < 7; ++b) B[b] = *(const half8*)(p + b * (2 * XP2 * 16));
        // rotate chains: same-chain reuse gap = 4 MFMA issues (~32 cyc)
        a0e = __builtin_amdgcn_mfma_f32_32x32x16_f16(A[0], B[0], a0e, 0, 0, 0);
        a1e = __builtin_amdgcn_mfma_f32_32x32x16_f16(A[0], B[2], a1e, 0, 0, 0);
        a0o = __builtin_amdgcn_mfma_f32_32x32x16_f16(A[1], B[1], a0o, 0, 0, 0);
        a1o = __builtin_amdgcn_mfma_f32_32x32x16_f16(A[1], B[3], a1o, 0, 0, 0);
        a0e = __builtin_amdgcn_mfma_f32_32x32x16_f16(A[2], B[2], a0e, 0, 0, 0);
        a1e = __builtin_amdgcn_mfma_f32_32x32x16_f16(A[2], B[4], a1e, 0, 0, 0);
        a0o = __builtin_amdgcn_mfma_f32_32x32x16_f16(A[3], B[3], a0o, 0, 0, 0);
        a1o = __builtin_amdgcn_mfma_f32_32x32x16_f16(A[3], B[5], a1o, 0, 0, 0);
        a0e = __builtin_amdgcn_mfma_f32_32x32x16_f16(A[4], B[4], a0e, 0, 0, 0);
        a1e = __builtin_amdgcn_mfma_f32_32x32x16_f16(A[4], B[6], a1e, 0, 0, 0);
    };

    half8 A0[5], A1[5];
    LDA(A0, 0);
    LDA(A1, 1);
#pragma unroll 1
    for (int kx = 0; kx < 40; kx += 2) {
        body(A0, kx);
        LDA(A0, kx + 2);          // <= 40
        body(A1, kx + 1);
        LDA(A1, kx + 3);          // <= 41 (zero-padded slab)
    }
    body(A0, 40);

#pragma unroll
    for (int r = 0; r < 16; ++r) { a0e[r] += a0o[r]; a1e[r] += a1o[r]; }

    // C/D layout (32x32): col = l&31, row = (r&3) + 8*(r>>2) + 4*(l>>5)
    float* op = out + (size_t)img * CONV * CONV;
    int colb = x0 + (wx << 5) + ln;
    int rb   = y0 + (l5 << 2);
#pragma unroll
    for (int r2 = 0; r2 < 16; ++r2) {
        int rowo = (r2 & 3) + ((r2 >> 2) << 3);
        op[(size_t)(rb + rowo) * CONV + colb]      = a0e[r2];
        op[(size_t)(rb + 32 + rowo) * CONV + colb] = a1e[r2];
    }
}

// ---------------- Kernel B: wave-streaming box-sums + Q, 2 chains/wave ----------------
template<int C, int RM, int BM, bool BC>
__device__ __forceinline__ float dppadd(float v) {
    int t = __builtin_amdgcn_update_dpp(0, __builtin_bit_cast(int, v), C, RM, BM, BC);
    return v + __builtin_bit_cast(float, t);
}

__device__ __forceinline__ float wave_iscan(float v) {
    v = dppadd<0x111, 0xf, 0xf, true >(v);   // row_shr:1
    v = dppadd<0x112, 0xf, 0xf, true >(v);   // row_shr:2
    v = dppadd<0x114, 0xf, 0xf, true >(v);   // row_shr:4
    v = dppadd<0x118, 0xf, 0xf, true >(v);   // row_shr:8
    v = dppadd<0x142, 0xa, 0xf, false>(v);   // row_bcast:15 -> rows 1,3
    v = dppadd<0x143, 0xc, 0xf, false>(v);   // row_bcast:31 -> rows 2,3
    return v;
}

__device__ __forceinline__ float win32(float s, int lane) {
    float P = wave_iscan(s);
    float Pg = __shfl(P, lane + 31, 64);
    return Pg - P + s;
}

__device__ __forceinline__ float qval(float A0, float A1, float A2, float A3) {
    float mul = A0 * A1;
    float sq  = fmaf(A0, A0, A1 * A1);
    float num = 4.f * fmaf(NN, A3, -mul) * mul;
    float dt  = fmaf(NN, A2, -sq);
    float den = dt * sq;
    bool  c1  = (dt == 0.f) && (sq != 0.f);
    float nn = num, dd = den;
    if (den == 0.f) { nn = c1 ? 2.f * mul : 1.f; dd = c1 ? sq : 1.f; }
    return nn * __builtin_amdgcn_rcpf(dd);
}

// pair p: chain A = rows [62p, 62p+30], chain B = rows [62p+31, ...]
__global__ __launch_bounds__(512) void box_q_wave2(
    const float* __restrict__ o,     // [NIMG][512][512]
    const float* __restrict__ lab,   // [NIMG][512][512]
    double* __restrict__ acc)        // acc[NIMG]
{
    int bid  = blockIdx.x;
    int img  = bid >> 4;
    int rr   = bid & 15;
    int pair = rr >> 1;
    int xblk = rr & 1;
    int wid  = threadIdx.x >> 6;
    int lane = threadIdx.x & 63;

    int c0 = xblk * 256 + wid * 32;
    int c  = c0 + lane;
    bool cvalid = c < CONV;
    int r0A = pair * 62;
    int r0B = r0A + 31;
    int nB  = min(31, QOUT - r0B);   // 31, except last pair: 16

    const float* op = o   + (size_t)img * CONV * CONV + c;
    const float* lp = lab + (size_t)img * CONV * CONV + c;

    float sA0=0,sA1=0,sA2=0,sA3=0, sB0=0,sB1=0,sB2=0,sB3=0;
#pragma unroll 2
    for (int k = 0; k < BS; ++k) {
        float ov=0, lv=0, ow=0, lw=0;
        if (cvalid) {
            ov = op[(size_t)(r0A + k) * CONV]; lv = lp[(size_t)(r0A + k) * CONV];
            ow = op[(size_t)(r0B + k) * CONV]; lw = lp[(size_t)(r0B + k) * CONV];
        }
        sA0 += ov; sA1 += lv;
        sA2 = fmaf(ov, ov, fmaf(lv, lv, sA2)); sA3 = fmaf(ov, lv, sA3);
        sB0 += ow; sB1 += lw;
        sB2 = fmaf(ow, ow, fmaf(lw, lw, sB2)); sB3 = fmaf(ow, lw, sB3);
    }

    int x = c0 + lane;
    bool xvalid = (lane < 32) && (x < QOUT);
    float qacc = 0.f;

#pragma unroll 1
    for (int i = 0; i < 31; ++i) {
        bool mA = (i < 30), mB = (i + 1 < nB);
        float oa=0,la2=0,ob=0,lb=0, oc=0,lc=0,od=0,ld=0;
        if (mA && cvalid) {
            oa = op[(size_t)(r0A + i + BS) * CONV]; la2 = lp[(size_t)(r0A + i + BS) * CONV];
            ob = op[(size_t)(r0A + i) * CONV];      lb  = lp[(size_t)(r0A + i) * CONV];
        }
        if (mB && cvalid) {
            oc = op[(size_t)(r0B + i + BS) * CONV]; lc = lp[(size_t)(r0B + i + BS) * CONV];
            od = op[(size_t)(r0B + i) * CONV];      ld = lp[(size_t)(r0B + i) * CONV];
        }

        {
            float A0 = win32(sA0, lane), A1 = win32(sA1, lane);
            float A2 = win32(sA2, lane), A3 = win32(sA3, lane);
            if (xvalid) qacc += qval(A0, A1, A2, A3);
        }
        if (i < nB) {
            float B0 = win32(sB0, lane), B1 = win32(sB1, lane);
            float B2 = win32(sB2, lane), B3 = win32(sB3, lane);
            if (xvalid) qacc += qval(B0, B1, B2, B3);
        }

        sA0 += oa - ob; sA1 += la2 - lb;
        sA2 = fmaf(oa, oa, fmaf(la2, la2, fmaf(ob, -ob, fmaf(lb, -lb, sA2))));
        sA3 = fmaf(oa, la2, fmaf(ob, -lb, sA3));
        sB0 += oc - od; sB1 += lc - ld;
        sB2 = fmaf(oc, oc, fmaf(lc, lc, fmaf(od, -od, fmaf(ld, -ld, sB2))));
        sB3 = fmaf(oc, lc, fmaf(od, -ld, sB3));
    }

    qacc += __shfl_down(qacc, 16, 64);
    qacc += __shfl_down(qacc, 8, 64);
    qacc += __shfl_down(qacc, 4, 64);
    qacc += __shfl_down(qacc, 2, 64);
    qacc += __shfl_down(qacc, 1, 64);
    if (lane == 0) atomicAdd(&acc[img], (double)qacc);
}

__global__ void finalize_kernel(const double* __restrict__ acc, float* __restrict__ out)
{
    double t = 0.0;
    for (int i = 0; i < NIMG; ++i) t += acc[i];
    out[0] = 1.0f - (float)(t / 7403552.0);   // 4*8*481*481
}

extern "C" void kernel_launch(void* const* d_in, const int* in_sizes, int n_in,
                              void* d_out, int out_size, void* d_ws, size_t ws_size,
                              hipStream_t stream)
{
    const float* outputs = (const float*)d_in[0];   // [4,8,552,552]
    const float* labels  = (const float*)d_in[1];   // [4,8,512,512]
    const float* mtf     = (const float*)d_in[2];   // [8,1,41,41]

    double*    acc   = (double*)d_ws;                                   // @0
    float*     o_buf = (float*)((char*)d_ws + 4096);                    // 33.55 MB
    _Float16*  T     = (_Float16*)((char*)d_ws + 4096 + 33554432);      // 20.64 MB
    _Float16*  Atab  = (_Float16*)((char*)d_ws + 4096 + 33554432 + 20643840); // 2.15 MB

    hipMemsetAsync(d_ws, 0, 256, stream);

    prep_transpose<<<NIMG * 81, 256, 0, stream>>>(outputs, T);
    prep_atab32<<<NBANDS * KXP, 320, 0, stream>>>(mtf, Atab);
    conv_mfma4c<<<NIMG * 32, 256, 14 * XP2 * 16, stream>>>(T, Atab, o_buf);
    box_q_wave2<<<NIMG * 16, 512, 0, stream>>>(o_buf, labels, acc);
    finalize_kernel<<<1, 1, 0, stream>>>(acc, (float*)d_out);
}